// Round 5
// baseline (26.480 us; speedup 1.0000x reference)
//
#include <hip/hip_runtime.h>

#define B_ 2
#define H_ 352
#define W_ 1216
#define HW_ (H_ * W_)      // 428032
#define K_ 9
#define TW 64              // tile width (pixels)
#define TH 8               // tile height
#define SOFF 8             // halo margin (16B-aligned halo base)
#define SR (TH + 2 * SOFF) // 24 staged rows
#define SC (TW + 2 * SOFF) // 80 staged cols
#define NBX (W_ / TW)      // 19
#define NBY (H_ / TH)      // 44
#define NBLK (B_ * NBX * NBY)  // 1672
#define NV4 (SR * (SC / 4))    // 480 float4 stage elements

typedef float v4 __attribute__((ext_vector_type(4)));
typedef float v2 __attribute__((ext_vector_type(2)));

__global__ __launch_bounds__(256) void dcn_post_kernel(
    const float* __restrict__ depth,
    const float* __restrict__ weight,
    const float* __restrict__ offset,
    const float* __restrict__ wtap,
    const float* __restrict__ bias,
    float* __restrict__ out)
{
    __shared__ float sm[SR * SC];   // 7680 B

    const int bid = blockIdx.x;
    const int b   = bid / (NBX * NBY);
    const int r2  = bid - b * (NBX * NBY);
    const int by  = r2 / NBX;
    const int bx  = r2 - by * NBX;
    const int tid = threadIdx.x;
    const int txp = tid & 31;          // x-pair index 0..31
    const int ty  = tid >> 5;          // row 0..7

    const int x  = bx * TW + txp * 2;  // even -> 8B-aligned float2 streams
    const int y  = by * TH + ty;
    const int oy = by * TH - SOFF;
    const int ox = bx * TW - SOFF;     // multiple of 8 -> float4 staging aligned
    const int p  = y * W_ + x;

    const float* __restrict__ dpt = depth + b * HW_;

    // ---- stage 24x80 depth halo into LDS via predicated float4 ----
    for (int i = tid; i < NV4; i += 256) {
        const int r  = i / (SC / 4);
        const int c4 = (i - r * (SC / 4)) * 4;
        const int gy = oy + r;
        const int gx = ox + c4;        // multiple of 4; fully in or out
        v4 v = 0.f;
        if ((unsigned)gy < (unsigned)H_ && (unsigned)gx < (unsigned)W_)
            v = *reinterpret_cast<const v4*>(dpt + gy * W_ + gx);
        *reinterpret_cast<v4*>(sm + r * SC + c4) = v;
    }

    // ---- batch-prefetch ALL streamed values as float2 (latency overlaps barrier) ----
    float wt[K_];
#pragma unroll
    for (int k = 0; k < K_; ++k) wt[k] = wtap[k];
    const float bv = bias[0];

    const float* obase = offset + (size_t)b * 2 * K_ * HW_ + p;
    v2 ody[K_], odx[K_];
#pragma unroll
    for (int k = 0; k < K_; ++k) {
        ody[k] = *reinterpret_cast<const v2*>(obase + (2 * k) * HW_);
        odx[k] = *reinterpret_cast<const v2*>(obase + (2 * k + 1) * HW_);
    }

    const float* wbase = weight + (size_t)b * K_ * HW_ + p;
    v2 wg[K_];
    v2 ms = 0.f;
#pragma unroll
    for (int k = 0; k < K_; ++k) {
        wg[k] = *reinterpret_cast<const v2*>(wbase + k * HW_);
        ms += wg[k];
    }
    ms *= (1.f / 9.f);

    __syncthreads();

    const int lxc = txp * 2 + SOFF;
    const int lyc = ty + SOFF;
    v2 dv;
    dv[0] = sm[lyc * SC + lxc];
    dv[1] = sm[lyc * SC + lxc + 1];

    v2 acc = 0.f;
#pragma unroll
    for (int k = 0; k < K_; ++k) {
        const float ky = (float)(y + (k / 3) - 1);
        const float kx = (float)(x + (k % 3) - 1);
        const float wk = wt[k];
#pragma unroll
        for (int i = 0; i < 2; ++i) {
            const float py = ky + ody[k][i];
            const float px = kx + (float)i + odx[k][i];
            const float y0f = floorf(py);
            const float x0f = floorf(px);
            const float fy = py - y0f;
            const float fx = px - x0f;
            const int yi0 = (int)y0f, xi0 = (int)x0f;

            const int ly = yi0 - oy;       // need [0, SR-2]
            const int lx = xi0 - ox;       // need [0, SC-2]
            float v00, v01, v10, v11;
            if ((unsigned)ly <= (SR - 2) && (unsigned)lx <= (SC - 2)) {
                const float* s = sm + ly * SC + lx;
                v00 = s[0];
                v01 = s[1];
                v10 = s[SC];
                v11 = s[SC + 1];
            } else {
                // ultra-rare fallback (|offset| > ~7): zero-padded global gather
                const int yi1 = yi0 + 1, xi1 = xi0 + 1;
                const bool vy0 = (unsigned)yi0 < (unsigned)H_;
                const bool vy1 = (unsigned)yi1 < (unsigned)H_;
                const bool vx0 = (unsigned)xi0 < (unsigned)W_;
                const bool vx1 = (unsigned)xi1 < (unsigned)W_;
                const int r0 = yi0 * W_;
                const int r1 = r0 + W_;
                v00 = (vy0 && vx0) ? dpt[r0 + xi0] : 0.f;
                v01 = (vy0 && vx1) ? dpt[r0 + xi1] : 0.f;
                v10 = (vy1 && vx0) ? dpt[r1 + xi0] : 0.f;
                v11 = (vy1 && vx1) ? dpt[r1 + xi1] : 0.f;
            }

            const float gy = 1.f - fy, gx = 1.f - fx;
            const float val = v00 * gy * gx + v01 * gy * fx
                            + v10 * fy * gx + v11 * fy * fx;
            acc[i] = fmaf((wg[k][i] - ms[i]) * wk, val, acc[i]);
        }
    }

    const v2 res = acc + bv + dv;
    *reinterpret_cast<v2*>(out + b * HW_ + p) = res;
}

extern "C" void kernel_launch(void* const* d_in, const int* in_sizes, int n_in,
                              void* d_out, int out_size, void* d_ws, size_t ws_size,
                              hipStream_t stream) {
    const float* depth  = (const float*)d_in[0];
    const float* weight = (const float*)d_in[1];
    const float* offset = (const float*)d_in[2];
    const float* wtap   = (const float*)d_in[3];
    const float* bias   = (const float*)d_in[4];
    float* out = (float*)d_out;

    dim3 grid(NBLK), block(256);
    hipLaunchKernelGGL(dcn_post_kernel, grid, block, 0, stream,
                       depth, weight, offset, wtap, bias, out);
}

// Round 6
// 24.618 us; speedup vs baseline: 1.0756x; 1.0756x over previous
//
#include <hip/hip_runtime.h>

#define B_ 2
#define H_ 352
#define W_ 1216
#define HW_ (H_ * W_)      // 428032
#define K_ 9
#define TW 64              // tile width (pixels)
#define TH 8               // tile height
#define SOFF 8             // halo margin (16B-aligned halo base)
#define SR (TH + 2 * SOFF) // 24 staged rows
#define SC (TW + 2 * SOFF) // 80 staged cols
#define NBX (W_ / TW)      // 19
#define NBY (H_ / TH)      // 44
#define NBLK (B_ * NBX * NBY)  // 1672 blocks x 512 threads
#define NV4 (SR * (SC / 4))    // 480 float4 stage elements

typedef float v4 __attribute__((ext_vector_type(4)));

__global__ __launch_bounds__(512) void dcn_post_kernel(
    const float* __restrict__ depth,
    const float* __restrict__ weight,
    const float* __restrict__ offset,
    const float* __restrict__ wtap,
    const float* __restrict__ bias,
    float* __restrict__ out)
{
    __shared__ float sm[SR * SC];   // 7680 B

    const int bid = blockIdx.x;
    const int b   = bid / (NBX * NBY);
    const int r2  = bid - b * (NBX * NBY);
    const int by  = r2 / NBX;
    const int bx  = r2 - by * NBX;
    const int tid = threadIdx.x;
    const int tx  = tid & (TW - 1);    // 0..63
    const int ty  = tid >> 6;          // 0..7

    const int y  = by * TH + ty;
    const int x  = bx * TW + tx;
    const int oy = by * TH - SOFF;
    const int ox = bx * TW - SOFF;     // multiple of 4 -> float4 staging aligned
    const int p  = y * W_ + x;

    const float* __restrict__ dpt = depth + b * HW_;

    // ---- stage 24x80 depth halo into LDS via predicated float4 (<=1 per thread) ----
    if (tid < NV4) {
        const int r  = tid / (SC / 4);
        const int c4 = (tid - r * (SC / 4)) * 4;
        const int gy = oy + r;
        const int gx = ox + c4;        // multiple of 4; fully in or out
        v4 v = 0.f;
        if ((unsigned)gy < (unsigned)H_ && (unsigned)gx < (unsigned)W_)
            v = *reinterpret_cast<const v4*>(dpt + gy * W_ + gx);
        *reinterpret_cast<v4*>(sm + r * SC + c4) = v;
    }

    // ---- batch-prefetch ALL streamed per-pixel values (latency overlaps barrier) ----
    float wt[K_];
#pragma unroll
    for (int k = 0; k < K_; ++k) wt[k] = wtap[k];
    const float bv = bias[0];

    const float* obase = offset + (size_t)b * 2 * K_ * HW_ + p;
    float ody[K_], odx[K_];
#pragma unroll
    for (int k = 0; k < K_; ++k) {
        ody[k] = obase[(2 * k) * HW_];
        odx[k] = obase[(2 * k + 1) * HW_];
    }

    const float* wbase = weight + (size_t)b * K_ * HW_ + p;
    float wg[K_];
    float m = 0.f;
#pragma unroll
    for (int k = 0; k < K_; ++k) {
        wg[k] = wbase[k * HW_];
        m += wg[k];
    }
    m *= (1.f / 9.f);

    __syncthreads();

    const float dval = sm[(ty + SOFF) * SC + (tx + SOFF)];

    float acc = 0.f;
#pragma unroll
    for (int k = 0; k < K_; ++k) {
        const float py = (float)(y + (k / 3) - 1) + ody[k];
        const float px = (float)(x + (k % 3) - 1) + odx[k];
        const float y0f = floorf(py);
        const float x0f = floorf(px);
        const float fy = py - y0f;
        const float fx = px - x0f;
        const int yi0 = (int)y0f, xi0 = (int)x0f;

        const int ly = yi0 - oy;           // need [0, SR-2]
        const int lx = xi0 - ox;           // need [0, SC-2]
        float v00, v01, v10, v11;
        if ((unsigned)ly <= (SR - 2) && (unsigned)lx <= (SC - 2)) {
            const float* s = sm + ly * SC + lx;
            v00 = s[0];
            v01 = s[1];
            v10 = s[SC];
            v11 = s[SC + 1];
        } else {
            // ultra-rare fallback (|offset| > ~7): zero-padded global gather
            const int yi1 = yi0 + 1, xi1 = xi0 + 1;
            const bool vy0 = (unsigned)yi0 < (unsigned)H_;
            const bool vy1 = (unsigned)yi1 < (unsigned)H_;
            const bool vx0 = (unsigned)xi0 < (unsigned)W_;
            const bool vx1 = (unsigned)xi1 < (unsigned)W_;
            const int r0 = yi0 * W_;
            const int r1 = r0 + W_;
            v00 = (vy0 && vx0) ? dpt[r0 + xi0] : 0.f;
            v01 = (vy0 && vx1) ? dpt[r0 + xi1] : 0.f;
            v10 = (vy1 && vx0) ? dpt[r1 + xi0] : 0.f;
            v11 = (vy1 && vx1) ? dpt[r1 + xi1] : 0.f;
        }

        const float gy = 1.f - fy, gx = 1.f - fx;
        const float val = v00 * gy * gx + v01 * gy * fx
                        + v10 * fy * gx + v11 * fy * fx;
        acc = fmaf((wg[k] - m) * wt[k], val, acc);
    }

    out[b * HW_ + p] = acc + bv + dval;
}

extern "C" void kernel_launch(void* const* d_in, const int* in_sizes, int n_in,
                              void* d_out, int out_size, void* d_ws, size_t ws_size,
                              hipStream_t stream) {
    const float* depth  = (const float*)d_in[0];
    const float* weight = (const float*)d_in[1];
    const float* offset = (const float*)d_in[2];
    const float* wtap   = (const float*)d_in[3];
    const float* bias   = (const float*)d_in[4];
    float* out = (float*)d_out;

    dim3 grid(NBLK), block(512);
    hipLaunchKernelGGL(dcn_post_kernel, grid, block, 0, stream,
                       depth, weight, offset, wtap, bias, out);
}